// Round 13
// baseline (158.578 us; speedup 1.0000x reference)
//
#include <hip/hip_runtime.h>
#include <stdint.h>

// Problem constants (fixed by setup_inputs)
#define B_  8
#define N_  4096
#define O_  32
#define K_  16
#define BN_ (B_ * N_)          // 32768 points
#define PF_ (B_ * 64 * N_)     // 2097152 floats: point_feature
#define CB_ 256                // blocks for kC/kE (128 points each)
#define RPB 4                  // rows per kF block (4 waves x 1 row)
#define CHK 512                // candidates per staged chunk in kF
#define NCHK (N_ / CHK)        // 8 chunks
// d_out: [PF_] point_feature ([B][64][N]) then [BN_*K_] idx written as floats

// Workspace layout (float offsets): round-0's proven-passing layout (8.80 MB).
// The enlarged kC partial buffer (CB_*64) aliases WS_MAXV: kC->kE prologue
// complete before kF writes SEL (same stream), so lifetimes are disjoint.
enum : int {
  WS_PARTA = 0,                   // 64*9   per-block partial moments of xyz
  WS_XX    = 1024,                // BN_    xx[b,n] = sum_c x^2 (exact ref rounding)
  WS_SC0   = WS_XX + BN_,         // 32     BN0 scale
  WS_SH0   = WS_SC0 + 32,         // 32     BN0 shift
  WS_PARTC = WS_SH0 + 32,         // (legacy 64*64 region, unused)
  WS_SC1   = WS_PARTC + 4096,     // 32     (legacy, unused after kD fusion)
  WS_SH1   = WS_SC1 + 32,         // 32     (legacy, unused)
  WS_MAXV  = WS_SH1 + 32,         // BN_*32 SEL: alpha-selected extremum of res
  WS_MINV  = WS_MAXV + BN_ * 32,  // BN_*32 (unused now; layout kept verbatim)
  WS_ROWS  = WS_MINV + BN_ * 32,  // BN_*2  per-row (sum, sumsq) of res
  WS_DEN   = WS_ROWS + BN_ * 2,   // 8      (legacy, unused after kG fusion)
  WS_TOTAL = WS_DEN + 8
};
#define WS_PARTC2 WS_MAXV          // CB_*64 kC partials, time-aliased onto SEL

// ---------------- Kernel A: xx precompute + global xyz moments ----------------
// xx must match ref bitwise: sum(x*x,axis=1) reduce = (x0^2 + x1^2) + x2^2, no fma.
__global__ __launch_bounds__(256) void kA(const float* __restrict__ xyz,
                                          float* __restrict__ ws) {
  int tid = threadIdx.x;
  int gid = blockIdx.x * 256 + tid;
  float s0 = 0.f, s1 = 0.f, s2 = 0.f;
  float m00 = 0.f, m01 = 0.f, m02 = 0.f, m11 = 0.f, m12 = 0.f, m22 = 0.f;
  for (int i = gid; i < BN_; i += 64 * 256) {
    int b = i >> 12, n = i & (N_ - 1);
    const float* xb = xyz + b * 3 * N_;
    float x0 = xb[n], x1 = xb[N_ + n], x2 = xb[2 * N_ + n];
    float xx = __fadd_rn(__fadd_rn(__fmul_rn(x0, x0), __fmul_rn(x1, x1)),
                         __fmul_rn(x2, x2));
    ws[WS_XX + i] = xx;
    s0 += x0; s1 += x1; s2 += x2;
    m00 = fmaf(x0, x0, m00); m01 = fmaf(x0, x1, m01); m02 = fmaf(x0, x2, m02);
    m11 = fmaf(x1, x1, m11); m12 = fmaf(x1, x2, m12); m22 = fmaf(x2, x2, m22);
  }
  __shared__ float sd[256];
  float acc[9] = {s0, s1, s2, m00, m01, m02, m11, m12, m22};
#pragma unroll
  for (int q = 0; q < 9; ++q) {
    sd[tid] = acc[q];
    __syncthreads();
    for (int s = 128; s > 0; s >>= 1) {
      if (tid < s) sd[tid] += sd[tid + s];
      __syncthreads();
    }
    if (tid == 0) ws[WS_PARTA + blockIdx.x * 9 + q] = sd[0];
    __syncthreads();
  }
}

// ---------------- Kernel C (+fused kB): BN0 stats + y1 stats pass ----------------
__global__ __launch_bounds__(256) void kC(const float* __restrict__ xyz,
                                          const float* __restrict__ w0,
                                          const float* __restrict__ g0,
                                          const float* __restrict__ b0,
                                          const float* __restrict__ w1,
                                          float* __restrict__ ws) {
  __shared__ float S9[9];
  __shared__ float w0s[96], sc0s[32], sh0s[32], w1s[32 * 33], xs[8][33], red[256];
  int tid = threadIdx.x;
  // --- fused kB prologue (verbatim reduction order) ---
  if (tid < 9) {
    float s = 0.f;
    for (int blk = 0; blk < 64; ++blk) s += ws[WS_PARTA + blk * 9 + tid];
    S9[tid] = s;
  }
  if (tid < 96) w0s[tid] = w0[tid];
  for (int i = tid; i < 1024; i += 256) w1s[(i >> 5) * 33 + (i & 31)] = w1[i];
  __syncthreads();
  if (tid < 32) {
    const float inv = 1.0f / 32768.0f;
    float mc0 = S9[0] * inv, mc1 = S9[1] * inv, mc2 = S9[2] * inv;
    float M00 = S9[3] * inv, M01 = S9[4] * inv, M02 = S9[5] * inv;
    float M11 = S9[6] * inv, M12 = S9[7] * inv, M22 = S9[8] * inv;
    float w0c = w0[tid * 3], w1c = w0[tid * 3 + 1], w2c = w0[tid * 3 + 2];
    float m = w0c * mc0 + w1c * mc1 + w2c * mc2;
    float e2 = w0c * w0c * M00 + w1c * w1c * M11 + w2c * w2c * M22 +
               2.f * (w0c * w1c * M01 + w0c * w2c * M02 + w1c * w2c * M12);
    float v = fmaxf(e2 - m * m, 0.f);
    float sc = g0[tid] / sqrtf(v + 1e-5f);
    float sh = b0[tid] - m * sc;
    sc0s[tid] = sc; sh0s[tid] = sh;
    if (blockIdx.x == 0) { ws[WS_SC0 + tid] = sc; ws[WS_SH0 + tid] = sh; }
  }
  __syncthreads();
  // --- kC body ---
  int p = tid >> 5, o = tid & 31;
  float S = 0.f, S2 = 0.f;
  for (int it = 0; it < 16; ++it) {
    int i = blockIdx.x * 128 + it * 8 + p;
    int b = i >> 12, n = i & (N_ - 1);
    const float* xb = xyz + b * 3 * N_;
    float x0 = xb[n], x1 = xb[N_ + n], x2 = xb[2 * N_ + n];
    float y0 = x0 * w0s[o * 3] + x1 * w0s[o * 3 + 1] + x2 * w0s[o * 3 + 2];
    float a = y0 * sc0s[o] + sh0s[o];
    xs[p][o] = (a >= 0.f) ? a : 0.1f * a;
    __syncthreads();
    float y1 = 0.f;
#pragma unroll
    for (int c = 0; c < 32; ++c) y1 = fmaf(w1s[o * 33 + c], xs[p][c], y1);
    S += y1; S2 = fmaf(y1, y1, S2);
    __syncthreads();
  }
  red[tid] = S;
  __syncthreads();
  if (p == 0) {
    float t = 0.f;
    for (int pp = 0; pp < 8; ++pp) t += red[pp * 32 + o];
    ws[WS_PARTC2 + blockIdx.x * 64 + o] = t;
  }
  __syncthreads();
  red[tid] = S2;
  __syncthreads();
  if (p == 0) {
    float t = 0.f;
    for (int pp = 0; pp < 8; ++pp) t += red[pp * 32 + o];
    ws[WS_PARTC2 + blockIdx.x * 64 + 32 + o] = t;
  }
}

// ---------------- Kernel E (+fused kD): write x-branch (out ch 0..31) ----------------
__global__ __launch_bounds__(256) void kE(const float* __restrict__ xyz,
                                          const float* __restrict__ w0,
                                          const float* __restrict__ w1,
                                          const float* __restrict__ g1,
                                          const float* __restrict__ b1,
                                          const float* __restrict__ ws,
                                          float* __restrict__ out) {
  __shared__ float w0s[96], sc0s[32], sh0s[32], sc1s[32], sh1s[32], w1s[32 * 33],
      xs[8][33];
  int tid = threadIdx.x;
  if (tid < 96) w0s[tid] = w0[tid];
  if (tid < 32) {
    sc0s[tid] = ws[WS_SC0 + tid]; sh0s[tid] = ws[WS_SH0 + tid];
    // --- fused kD (verbatim reduction order) ---
    float S = 0.f, S2 = 0.f;
    for (int blk = 0; blk < CB_; ++blk) {
      S += ws[WS_PARTC2 + blk * 64 + tid];
      S2 += ws[WS_PARTC2 + blk * 64 + 32 + tid];
    }
    float m = S / 32768.f;
    float v = fmaxf(S2 / 32768.f - m * m, 0.f);
    float sc = g1[tid] / sqrtf(v + 1e-5f);
    sc1s[tid] = sc; sh1s[tid] = b1[tid] - m * sc;
  }
  for (int i = tid; i < 1024; i += 256) w1s[(i >> 5) * 33 + (i & 31)] = w1[i];
  __syncthreads();
  int p = tid >> 5, o = tid & 31;
  int o2 = tid >> 3, p2 = tid & 7;
  for (int it = 0; it < 16; ++it) {
    int i = blockIdx.x * 128 + it * 8 + p;
    int b = i >> 12, n = i & (N_ - 1);
    const float* xb = xyz + b * 3 * N_;
    float x0 = xb[n], x1 = xb[N_ + n], x2 = xb[2 * N_ + n];
    float y0 = x0 * w0s[o * 3] + x1 * w0s[o * 3 + 1] + x2 * w0s[o * 3 + 2];
    float a = y0 * sc0s[o] + sh0s[o];
    xs[p][o] = (a >= 0.f) ? a : 0.1f * a;
    __syncthreads();
    float y1 = 0.f;
#pragma unroll
    for (int c = 0; c < 32; ++c) y1 = fmaf(w1s[o * 33 + c], xs[p][c], y1);
    float z = y1 * sc1s[o] + sh1s[o];
    float x1v = (z >= 0.f) ? z : 0.1f * z;
    __syncthreads();           // all xs reads done
    xs[p][o] = x1v;            // reuse as transpose buffer
    __syncthreads();
    int i2 = blockIdx.x * 128 + it * 8 + p2;
    int b2 = i2 >> 12, n2 = i2 & (N_ - 1);
    out[b2 * 64 * N_ + o2 * N_ + n2] = xs[p2][o2];
    __syncthreads();
  }
}

// ---------------- Kernel F: exact kNN top-16 + fused gp extremum/stats ----------------
// R12 frame with the R8-proven 4-array data path restored: sxx staged in LDS
// (1 extra ds_read) replaces the 5-op xx recompute — R12's counters showed kF
// is VALU-issue-bound (80%), so trading 5 VALU for 1 LDS read wins. Key math is
// verbatim R8: dot(3) + inner(1, inline -2.0) + t(1, -pw modifier) + pn(1) +
// min(1) = 7 VALU/cand. All vector candidate loads remain BANNED (R2/3/4/9).
// gp phase writes the alpha-selected extremum (SEL) only — R2-R4-proven.
__global__ __launch_bounds__(256) void kF(const float* __restrict__ xyz,
                                          const float* __restrict__ w_nn,
                                          const float* __restrict__ alpha,
                                          float* __restrict__ out,
                                          float* __restrict__ ws) {
  int tid = threadIdx.x;
  int wave = tid >> 6, lane = tid & 63;
  int row = blockIdx.x * RPB + wave;  // b*N + n
  int b = row >> 12, n = row & (N_ - 1);
  const float* xb = xyz + b * 3 * N_;
  const float* xxp = ws + WS_XX + b * N_;
  float qx = xb[n], qy = xb[N_ + n], qz = xb[2 * N_ + n];
  float xxn = xxp[n];

  __shared__ float sx[2][CHK], sy[2][CHK], sz[2][CHK], sxx[2][CHK];  // 16 KB
  __shared__ unsigned long long list[RPB][64];                       // 2 KB
  __shared__ float rb[RPB][16][33];                                  // 8.4 KB

  // Phase 1: double-buffered scalar staging (R8-verbatim) + keys + running min
  float keys[64];
  float mn = __builtin_inff();
  float rx0, rx1, ry0, ry1, rz0, rz1, rw0, rw1;
  rx0 = xb[tid];           rx1 = xb[tid + 256];
  ry0 = xb[N_ + tid];      ry1 = xb[N_ + tid + 256];
  rz0 = xb[2 * N_ + tid];  rz1 = xb[2 * N_ + tid + 256];
  rw0 = xxp[tid];          rw1 = xxp[tid + 256];
#pragma unroll
  for (int c = 0; c < NCHK; ++c) {
    int buf = c & 1;
    sx[buf][tid] = rx0;  sx[buf][tid + 256] = rx1;
    sy[buf][tid] = ry0;  sy[buf][tid + 256] = ry1;
    sz[buf][tid] = rz0;  sz[buf][tid + 256] = rz1;
    sxx[buf][tid] = rw0; sxx[buf][tid + 256] = rw1;
    __syncthreads();     // staging visible; also fences next overwrite
    if (c + 1 < NCHK) {  // issue next chunk's loads now (hidden under compute)
      int i0 = (c + 1) * CHK + tid;
      rx0 = xb[i0];           rx1 = xb[i0 + 256];
      ry0 = xb[N_ + i0];      ry1 = xb[N_ + i0 + 256];
      rz0 = xb[2 * N_ + i0];  rz1 = xb[2 * N_ + i0 + 256];
      rw0 = xxp[i0];          rw1 = xxp[i0 + 256];
    }
#pragma unroll
    for (int jj = 0; jj < CHK / 64; ++jj) {
      int ml = (jj << 6) | lane;
      float px = sx[buf][ml], py = sy[buf][ml], pz = sz[buf][ml];
      float pw = sxx[buf][ml];
      float dot = __fmaf_rn(pz, qz, __fmaf_rn(py, qy, __fmul_rn(px, qx)));
      float inner = __fmul_rn(-2.0f, dot);
      float t = __fsub_rn(-pw, inner);   // (-xx[m]) - inner
      float pn = __fsub_rn(xxn, t);      // = -pd, exact
      keys[c * (CHK / 64) + jj] = pn;
      mn = fminf(mn, pn);
    }
    __syncthreads();     // all waves done reading buf before it's overwritten
  }

  // Phase 2: map lane-min once, bitonic sort u32 asc; T = 16th smallest
  unsigned e;
  {
    unsigned u = __float_as_uint(mn);
    u ^= ((unsigned)((int)u >> 31)) | 0x80000000u;  // float total order -> u32
    e = u;
  }
#pragma unroll
  for (int k = 2; k <= 64; k <<= 1) {
#pragma unroll
    for (int d = k >> 1; d >= 1; d >>= 1) {
      unsigned pe = __shfl_xor(e, d, 64);
      bool up = ((lane & k) == 0);
      bool lower = ((lane & d) == 0);
      unsigned lo = (e < pe) ? e : pe;
      unsigned hi = (e < pe) ? pe : e;
      e = (up == lower) ? lo : hi;
    }
  }
  unsigned tm = __shfl(e, 15, 64);
  unsigned tfu = (tm & 0x80000000u) ? (tm ^ 0x80000000u) : ~tm;  // inverse map
  float T = __uint_as_float(tfu);

  // Phase 3: rescan float keys, map survivors exactly, ballot-ranked compaction
  list[wave][lane] = ~0ull;
  __syncthreads();
  int base = 0;
#pragma unroll
  for (int j = 0; j < 64; ++j) {
    bool pred = (keys[j] <= T);
    unsigned long long mask = __ballot(pred);
    if (mask != 0ull) {
      if (pred) {
        unsigned uu = __float_as_uint(keys[j]);
        uu ^= ((unsigned)((int)uu >> 31)) | 0x80000000u;
        int rank = __popcll(mask & ((1ull << lane) - 1ull));
        int slot = base + rank;
        if (slot < 64)
          list[wave][slot] = ((unsigned long long)uu << 32) |
                             (unsigned)((j << 6) | lane);
      }
      base += __popcll(mask);
    }
  }
  __syncthreads();

  // Phase 4: bitonic sort 64 u64 survivor entries ascending
  unsigned long long ev = list[wave][lane];
#pragma unroll
  for (int k = 2; k <= 64; k <<= 1) {
#pragma unroll
    for (int d = k >> 1; d >= 1; d >>= 1) {
      unsigned long long pe = __shfl_xor(ev, d, 64);
      bool up = ((lane & k) == 0);
      bool lower = ((lane & d) == 0);
      bool lt = (ev < pe);
      unsigned long long lo = lt ? ev : pe;
      unsigned long long hi = lt ? pe : ev;
      ev = (up == lower) ? lo : hi;
    }
  }
  int m = (int)(unsigned)(ev & 0xffffffffull);
  if (lane < 16) out[PF_ + row * 16 + lane] = (float)m;   // idx as float

  // gp: res = (x[:,m]-x[:,n]) . w_nn -> per-o alpha-selected extremum over k,
  // row sum/sumsq for the per-batch std
  float s = 0.f, s2 = 0.f;
  if (lane < 16) {
    float dx = __fsub_rn(xb[m], qx);
    float dy = __fsub_rn(xb[N_ + m], qy);
    float dz = __fsub_rn(xb[2 * N_ + m], qz);
#pragma unroll
    for (int o = 0; o < 32; ++o) {
      float r = __fmaf_rn(dz, w_nn[o * 3 + 2],
                __fmaf_rn(dy, w_nn[o * 3 + 1], __fmul_rn(dx, w_nn[o * 3])));
      rb[wave][lane][o] = r;
      s += r;
      s2 = __fmaf_rn(r, r, s2);
    }
  }
  __syncthreads();
  if (lane < 32) {
    float mx = -__builtin_inff(), mnv = __builtin_inff();
#pragma unroll
    for (int r = 0; r < 16; ++r) {
      float v = rb[wave][r][lane];
      mx = fmaxf(mx, v);
      mnv = fminf(mnv, v);
    }
    float al = alpha[lane];
    // max over k commutes exactly through the monotone /denom, *al, +be chain;
    // for al<0 the chain max is attained at the min of res.
    ws[WS_MAXV + row * 32 + lane] = (al >= 0.f) ? mx : mnv;
  }
#pragma unroll
  for (int off = 1; off < 64; off <<= 1) {
    s += __shfl_xor(s, off, 64);
    s2 += __shfl_xor(s2, off, 64);
  }
  if (lane == 0) {
    ws[WS_ROWS + row * 2] = s;
    ws[WS_ROWS + row * 2 + 1] = s2;
  }
}

// ---------------- Kernel H (+fused kG): write gp (out ch 32..63) ----------------
__global__ __launch_bounds__(256) void kH(const float* __restrict__ alpha,
                                          const float* __restrict__ beta,
                                          const float* __restrict__ ws,
                                          float* __restrict__ out) {
  int tid = threadIdx.x;
  int i = blockIdx.x * 256 + tid;          // i < B_*32*N_ by grid construction
  int b = i >> 17;                          // uniform within a block
  // --- fused kG (verbatim reduction order for this batch) ---
  float s = 0.f, s2 = 0.f;
  for (int q = tid; q < N_; q += 256) {
    s += ws[WS_ROWS + (b * N_ + q) * 2];
    s2 += ws[WS_ROWS + (b * N_ + q) * 2 + 1];
  }
  __shared__ float sd[256], sd2[256];
  __shared__ float den_s;
  sd[tid] = s; sd2[tid] = s2;
  __syncthreads();
  for (int st = 128; st > 0; st >>= 1) {
    if (tid < st) { sd[tid] += sd[tid + st]; sd2[tid] += sd2[tid + st]; }
    __syncthreads();
  }
  if (tid == 0) {
    const float M = 2097152.0f;  // N*K*O per batch
    float var = fmaxf((sd2[0] - sd[0] * (sd[0] / M)) / (M - 1.0f), 0.f);
    den_s = sqrtf(var) + 1e-5f;
  }
  __syncthreads();
  float denom = den_s;
  int n = i & (N_ - 1);
  int o = (i >> 12) & 31;
  float al = alpha[o], be = beta[o];
  float v = ws[WS_MAXV + (b * N_ + n) * 32 + o];   // SEL (alpha-selected in kF)
  out[b * 64 * N_ + (32 + o) * N_ + n] = __fadd_rn(__fmul_rn(al, v / denom), be);
}

extern "C" void kernel_launch(void* const* d_in, const int* in_sizes, int n_in,
                              void* d_out, int out_size, void* d_ws, size_t ws_size,
                              hipStream_t stream) {
  const float* xyz   = (const float*)d_in[0];
  const float* w_nn  = (const float*)d_in[1];
  const float* alpha = (const float*)d_in[2];
  const float* beta_a= (const float*)d_in[3];
  const float* w0    = (const float*)d_in[4];
  const float* g0    = (const float*)d_in[5];
  const float* b0    = (const float*)d_in[6];
  const float* w1    = (const float*)d_in[7];
  const float* g1    = (const float*)d_in[8];
  const float* b1    = (const float*)d_in[9];
  float* out = (float*)d_out;
  float* ws  = (float*)d_ws;   // needs WS_TOTAL*4 ~ 8.80 MB (round-0 proven)

  kA<<<64, 256, 0, stream>>>(xyz, ws);
  kC<<<CB_, 256, 0, stream>>>(xyz, w0, g0, b0, w1, ws);
  kE<<<CB_, 256, 0, stream>>>(xyz, w0, w1, g1, b1, ws, out);
  kF<<<BN_ / RPB, RPB * 64, 0, stream>>>(xyz, w_nn, alpha, out, ws);
  kH<<<(B_ * 32 * N_ + 255) / 256, 256, 0, stream>>>(alpha, beta_a, ws, out);
}

// Round 14
// 139.630 us; speedup vs baseline: 1.1357x; 1.1357x over previous
//
#include <hip/hip_runtime.h>
#include <stdint.h>

// Problem constants (fixed by setup_inputs)
#define B_  8
#define N_  4096
#define O_  32
#define K_  16
#define BN_ (B_ * N_)          // 32768 points
#define PF_ (B_ * 64 * N_)     // 2097152 floats: point_feature
#define CB_ 256                // blocks for kC/kE (128 points each)
#define RPB 4                  // rows per kF block (4 waves x 1 row)
#define CHK 512                // candidates per staged chunk in kF
#define NCHK (N_ / CHK)        // 8 chunks
// d_out: [PF_] point_feature ([B][64][N]) then [BN_*K_] idx written as floats

// Workspace layout (float offsets): round-0's proven-passing layout (8.80 MB).
// PARTC2 aliases WS_MAXV (kC->kE done before kF writes SEL); Y1 uses the
// otherwise-idle WS_MINV region (written by kC, read by kE, dead before kF's
// SEL/ROWS consumers run).
enum : int {
  WS_PARTA = 0,                   // 64*9   per-block partial moments of xyz
  WS_XX    = 1024,                // BN_    xx[b,n] = sum_c x^2 (exact ref rounding)
  WS_SC0   = WS_XX + BN_,         // 32     (legacy, unused)
  WS_SH0   = WS_SC0 + 32,         // 32     (legacy, unused)
  WS_PARTC = WS_SH0 + 32,         // (legacy 64*64 region, unused)
  WS_SC1   = WS_PARTC + 4096,     // 32     (legacy, unused)
  WS_SH1   = WS_SC1 + 32,         // 32     (legacy, unused)
  WS_MAXV  = WS_SH1 + 32,         // BN_*32 SEL: alpha-selected extremum of res
  WS_MINV  = WS_MAXV + BN_ * 32,  // BN_*32 Y1 buffer (kC -> kE)
  WS_ROWS  = WS_MINV + BN_ * 32,  // BN_*2  per-row (sum, sumsq) of res
  WS_DEN   = WS_ROWS + BN_ * 2,   // 8      (legacy, unused)
  WS_TOTAL = WS_DEN + 8
};
#define WS_PARTC2 WS_MAXV          // CB_*64 kC partials, time-aliased onto SEL
#define WS_Y1     WS_MINV          // BN_*32 y1 values (kC -> kE)

// ---------------- Kernel A: xx precompute + global xyz moments ----------------
// xx must match ref bitwise: sum(x*x,axis=1) reduce = (x0^2 + x1^2) + x2^2, no fma.
__global__ __launch_bounds__(256) void kA(const float* __restrict__ xyz,
                                          float* __restrict__ ws) {
  int tid = threadIdx.x;
  int gid = blockIdx.x * 256 + tid;
  float s0 = 0.f, s1 = 0.f, s2 = 0.f;
  float m00 = 0.f, m01 = 0.f, m02 = 0.f, m11 = 0.f, m12 = 0.f, m22 = 0.f;
  for (int i = gid; i < BN_; i += 64 * 256) {
    int b = i >> 12, n = i & (N_ - 1);
    const float* xb = xyz + b * 3 * N_;
    float x0 = xb[n], x1 = xb[N_ + n], x2 = xb[2 * N_ + n];
    float xx = __fadd_rn(__fadd_rn(__fmul_rn(x0, x0), __fmul_rn(x1, x1)),
                         __fmul_rn(x2, x2));
    ws[WS_XX + i] = xx;
    s0 += x0; s1 += x1; s2 += x2;
    m00 = fmaf(x0, x0, m00); m01 = fmaf(x0, x1, m01); m02 = fmaf(x0, x2, m02);
    m11 = fmaf(x1, x1, m11); m12 = fmaf(x1, x2, m12); m22 = fmaf(x2, x2, m22);
  }
  __shared__ float sd[256];
  float acc[9] = {s0, s1, s2, m00, m01, m02, m11, m12, m22};
#pragma unroll
  for (int q = 0; q < 9; ++q) {
    sd[tid] = acc[q];
    __syncthreads();
    for (int s = 128; s > 0; s >>= 1) {
      if (tid < s) sd[tid] += sd[tid + s];
      __syncthreads();
    }
    if (tid == 0) ws[WS_PARTA + blockIdx.x * 9 + q] = sd[0];
    __syncthreads();
  }
}

// ---------------- Kernel C (+fused kB): BN0 stats + y1 stats pass ----------------
// Also stores y1 to WS_Y1 (coalesced [i*32+o]) so kE need not recompute it.
__global__ __launch_bounds__(256) void kC(const float* __restrict__ xyz,
                                          const float* __restrict__ w0,
                                          const float* __restrict__ g0,
                                          const float* __restrict__ b0,
                                          const float* __restrict__ w1,
                                          float* __restrict__ ws) {
  __shared__ float S9[9];
  __shared__ float w0s[96], sc0s[32], sh0s[32], w1s[32 * 33], xs[8][33], red[256];
  int tid = threadIdx.x;
  // --- fused kB prologue (verbatim reduction order) ---
  if (tid < 9) {
    float s = 0.f;
    for (int blk = 0; blk < 64; ++blk) s += ws[WS_PARTA + blk * 9 + tid];
    S9[tid] = s;
  }
  if (tid < 96) w0s[tid] = w0[tid];
  for (int i = tid; i < 1024; i += 256) w1s[(i >> 5) * 33 + (i & 31)] = w1[i];
  __syncthreads();
  if (tid < 32) {
    const float inv = 1.0f / 32768.0f;
    float mc0 = S9[0] * inv, mc1 = S9[1] * inv, mc2 = S9[2] * inv;
    float M00 = S9[3] * inv, M01 = S9[4] * inv, M02 = S9[5] * inv;
    float M11 = S9[6] * inv, M12 = S9[7] * inv, M22 = S9[8] * inv;
    float w0c = w0[tid * 3], w1c = w0[tid * 3 + 1], w2c = w0[tid * 3 + 2];
    float m = w0c * mc0 + w1c * mc1 + w2c * mc2;
    float e2 = w0c * w0c * M00 + w1c * w1c * M11 + w2c * w2c * M22 +
               2.f * (w0c * w1c * M01 + w0c * w2c * M02 + w1c * w2c * M12);
    float v = fmaxf(e2 - m * m, 0.f);
    float sc = g0[tid] / sqrtf(v + 1e-5f);
    float sh = b0[tid] - m * sc;
    sc0s[tid] = sc; sh0s[tid] = sh;
  }
  __syncthreads();
  // --- kC body ---
  int p = tid >> 5, o = tid & 31;
  float S = 0.f, S2 = 0.f;
  for (int it = 0; it < 16; ++it) {
    int i = blockIdx.x * 128 + it * 8 + p;
    int b = i >> 12, n = i & (N_ - 1);
    const float* xb = xyz + b * 3 * N_;
    float x0 = xb[n], x1 = xb[N_ + n], x2 = xb[2 * N_ + n];
    float y0 = x0 * w0s[o * 3] + x1 * w0s[o * 3 + 1] + x2 * w0s[o * 3 + 2];
    float a = y0 * sc0s[o] + sh0s[o];
    xs[p][o] = (a >= 0.f) ? a : 0.1f * a;
    __syncthreads();
    float y1 = 0.f;
#pragma unroll
    for (int c = 0; c < 32; ++c) y1 = fmaf(w1s[o * 33 + c], xs[p][c], y1);
    ws[WS_Y1 + i * 32 + o] = y1;   // coalesced: addr = blk*4096 + it*256 + tid
    S += y1; S2 = fmaf(y1, y1, S2);
    __syncthreads();
  }
  red[tid] = S;
  __syncthreads();
  if (p == 0) {
    float t = 0.f;
    for (int pp = 0; pp < 8; ++pp) t += red[pp * 32 + o];
    ws[WS_PARTC2 + blockIdx.x * 64 + o] = t;
  }
  __syncthreads();
  red[tid] = S2;
  __syncthreads();
  if (p == 0) {
    float t = 0.f;
    for (int pp = 0; pp < 8; ++pp) t += red[pp * 32 + o];
    ws[WS_PARTC2 + blockIdx.x * 64 + 32 + o] = t;
  }
}

// ---------------- Kernel E (+fused kD): write x-branch (out ch 0..31) ----------------
// Light pass: reads kC's stored y1 (bit-identical to the old recompute),
// applies BN1 affine + leaky, transposes via xs, writes coalesced.
__global__ __launch_bounds__(256) void kE(const float* __restrict__ g1,
                                          const float* __restrict__ b1,
                                          const float* __restrict__ ws,
                                          float* __restrict__ out) {
  __shared__ float sc1s[32], sh1s[32], xs[8][33];
  int tid = threadIdx.x;
  if (tid < 32) {
    // --- fused kD (verbatim reduction order) ---
    float S = 0.f, S2 = 0.f;
    for (int blk = 0; blk < CB_; ++blk) {
      S += ws[WS_PARTC2 + blk * 64 + tid];
      S2 += ws[WS_PARTC2 + blk * 64 + 32 + tid];
    }
    float m = S / 32768.f;
    float v = fmaxf(S2 / 32768.f - m * m, 0.f);
    float sc = g1[tid] / sqrtf(v + 1e-5f);
    sc1s[tid] = sc; sh1s[tid] = b1[tid] - m * sc;
  }
  __syncthreads();
  int p = tid >> 5, o = tid & 31;
  int o2 = tid >> 3, p2 = tid & 7;
  for (int it = 0; it < 16; ++it) {
    int i = blockIdx.x * 128 + it * 8 + p;
    float y1 = ws[WS_Y1 + i * 32 + o];   // coalesced read
    float z = y1 * sc1s[o] + sh1s[o];
    float x1v = (z >= 0.f) ? z : 0.1f * z;
    xs[p][o] = x1v;
    __syncthreads();
    int i2 = blockIdx.x * 128 + it * 8 + p2;
    int b2 = i2 >> 12, n2 = i2 & (N_ - 1);
    out[b2 * 64 * N_ + o2 * N_ + n2] = xs[p2][o2];
    __syncthreads();           // all xs reads done before next overwrite
  }
}

// ---------------- Kernel F: exact kNN top-16 + fused gp extremum/stats ----------------
// R12-verbatim phases and key math (xx recomputed with kA's exact ops + asm
// guards; all vector candidate loads BANNED per R2/3/4/9). One change: list+rb
// (used only AFTER phase 1) are time-aliased onto the staging LDS (dead after
// phase 1's final barrier) — LDS 23.0 -> 12.3 KB, lifting the blocks/CU cap.
// Alias safety: final phase-1 __syncthreads() fences all staging reads; list
// and rb are per-wave-private slices; existing barriers cover cross-use.
__global__ __launch_bounds__(256) void kF(const float* __restrict__ xyz,
                                          const float* __restrict__ w_nn,
                                          const float* __restrict__ alpha,
                                          float* __restrict__ out,
                                          float* __restrict__ ws) {
  int tid = threadIdx.x;
  int wave = tid >> 6, lane = tid & 63;
  int row = blockIdx.x * RPB + wave;  // b*N + n
  int b = row >> 12, n = row & (N_ - 1);
  const float* xb = xyz + b * 3 * N_;
  const float* xxp = ws + WS_XX + b * N_;
  float qx = xb[n], qy = xb[N_ + n], qz = xb[2 * N_ + n];
  float xxn = xxp[n];

  // 12288 B arena: phase 1 = sx/sy/sz (2x512 floats each);
  // post-phase-1 alias = list (4x64 u64 = 2048 B) + rb (4x16x33 f = 8448 B).
  __shared__ __align__(16) char smem[12288];
  float* sxp = (float*)smem;            // [2*CHK]
  float* syp = (float*)(smem + 4096);   // [2*CHK]
  float* szp = (float*)(smem + 8192);   // [2*CHK]

  // Phase 1: double-buffered scalar staging + float keys in regs + running min
  float keys[64];
  float mn = __builtin_inff();
  float rx0, rx1, ry0, ry1, rz0, rz1;
  rx0 = xb[tid];           rx1 = xb[tid + 256];
  ry0 = xb[N_ + tid];      ry1 = xb[N_ + tid + 256];
  rz0 = xb[2 * N_ + tid];  rz1 = xb[2 * N_ + tid + 256];
#pragma unroll
  for (int c = 0; c < NCHK; ++c) {
    int buf = (c & 1) * CHK;
    sxp[buf + tid] = rx0;  sxp[buf + tid + 256] = rx1;
    syp[buf + tid] = ry0;  syp[buf + tid + 256] = ry1;
    szp[buf + tid] = rz0;  szp[buf + tid + 256] = rz1;
    __syncthreads();     // staging visible; also fences next overwrite
    if (c + 1 < NCHK) {  // issue next chunk's loads now (hidden under compute)
      int i0 = (c + 1) * CHK + tid;
      rx0 = xb[i0];           rx1 = xb[i0 + 256];
      ry0 = xb[N_ + i0];      ry1 = xb[N_ + i0 + 256];
      rz0 = xb[2 * N_ + i0];  rz1 = xb[2 * N_ + i0 + 256];
    }
#pragma unroll
    for (int jj = 0; jj < CHK / 64; ++jj) {
      int ml = buf + ((jj << 6) | lane);
      float px = sxp[ml], py = syp[ml], pz = szp[ml];
      // xx recomputed with kA's exact ops; asm guards inhibit pk-packing
      float m0 = __fmul_rn(px, px);
      float m1 = __fmul_rn(py, py);
      float m2 = __fmul_rn(pz, pz);
      asm volatile("" : "+v"(m0), "+v"(m1), "+v"(m2));
      float pw = __fadd_rn(__fadd_rn(m0, m1), m2);
      asm volatile("" : "+v"(pw));
      float dot = __fmaf_rn(pz, qz, __fmaf_rn(py, qy, __fmul_rn(px, qx)));
      asm volatile("" : "+v"(dot));
      float inner = __fmul_rn(-2.0f, dot);
      float t = __fsub_rn(-pw, inner);   // (-xx[m]) - inner
      float pn = __fsub_rn(xxn, t);      // = -pd, exact
      keys[c * (CHK / 64) + jj] = pn;
      mn = fminf(mn, pn);
    }
    __syncthreads();     // all waves done reading buf before it's overwritten
  }
  // staging arrays are DEAD from here; alias the arena:
  unsigned long long* listp = (unsigned long long*)smem;  // [RPB][64]
  float* rbp = (float*)(smem + 2048);                     // [RPB][16][33]

  // Phase 2: map lane-min once, bitonic sort u32 asc; T = 16th smallest
  unsigned e;
  {
    unsigned u = __float_as_uint(mn);
    u ^= ((unsigned)((int)u >> 31)) | 0x80000000u;  // float total order -> u32
    e = u;
  }
#pragma unroll
  for (int k = 2; k <= 64; k <<= 1) {
#pragma unroll
    for (int d = k >> 1; d >= 1; d >>= 1) {
      unsigned pe = __shfl_xor(e, d, 64);
      bool up = ((lane & k) == 0);
      bool lower = ((lane & d) == 0);
      unsigned lo = (e < pe) ? e : pe;
      unsigned hi = (e < pe) ? pe : e;
      e = (up == lower) ? lo : hi;
    }
  }
  unsigned tm = __shfl(e, 15, 64);
  unsigned tfu = (tm & 0x80000000u) ? (tm ^ 0x80000000u) : ~tm;  // inverse map
  float T = __uint_as_float(tfu);

  // Phase 3: rescan float keys, map survivors exactly, ballot-ranked compaction
  listp[wave * 64 + lane] = ~0ull;
  __syncthreads();
  int base = 0;
#pragma unroll
  for (int j = 0; j < 64; ++j) {
    bool pred = (keys[j] <= T);
    unsigned long long mask = __ballot(pred);
    if (mask != 0ull) {
      if (pred) {
        unsigned uu = __float_as_uint(keys[j]);
        uu ^= ((unsigned)((int)uu >> 31)) | 0x80000000u;
        int rank = __popcll(mask & ((1ull << lane) - 1ull));
        int slot = base + rank;
        if (slot < 64)
          listp[wave * 64 + slot] = ((unsigned long long)uu << 32) |
                                    (unsigned)((j << 6) | lane);
      }
      base += __popcll(mask);
    }
  }
  __syncthreads();

  // Phase 4: bitonic sort 64 u64 survivor entries ascending
  unsigned long long ev = listp[wave * 64 + lane];
#pragma unroll
  for (int k = 2; k <= 64; k <<= 1) {
#pragma unroll
    for (int d = k >> 1; d >= 1; d >>= 1) {
      unsigned long long pe = __shfl_xor(ev, d, 64);
      bool up = ((lane & k) == 0);
      bool lower = ((lane & d) == 0);
      bool lt = (ev < pe);
      unsigned long long lo = lt ? ev : pe;
      unsigned long long hi = lt ? pe : ev;
      ev = (up == lower) ? lo : hi;
    }
  }
  int m = (int)(unsigned)(ev & 0xffffffffull);
  if (lane < 16) out[PF_ + row * 16 + lane] = (float)m;   // idx as float

  // gp: res = (x[:,m]-x[:,n]) . w_nn -> per-o alpha-selected extremum over k,
  // row sum/sumsq for the per-batch std
  float s = 0.f, s2 = 0.f;
  if (lane < 16) {
    float dx = __fsub_rn(xb[m], qx);
    float dy = __fsub_rn(xb[N_ + m], qy);
    float dz = __fsub_rn(xb[2 * N_ + m], qz);
#pragma unroll
    for (int o = 0; o < 32; ++o) {
      float r = __fmaf_rn(dz, w_nn[o * 3 + 2],
                __fmaf_rn(dy, w_nn[o * 3 + 1], __fmul_rn(dx, w_nn[o * 3])));
      rbp[(wave * 16 + lane) * 33 + o] = r;
      s += r;
      s2 = __fmaf_rn(r, r, s2);
    }
  }
  __syncthreads();
  if (lane < 32) {
    float mx = -__builtin_inff(), mnv = __builtin_inff();
#pragma unroll
    for (int r = 0; r < 16; ++r) {
      float v = rbp[(wave * 16 + r) * 33 + lane];
      mx = fmaxf(mx, v);
      mnv = fminf(mnv, v);
    }
    float al = alpha[lane];
    // max over k commutes exactly through the monotone /denom, *al, +be chain;
    // for al<0 the chain max is attained at the min of res.
    ws[WS_MAXV + row * 32 + lane] = (al >= 0.f) ? mx : mnv;
  }
#pragma unroll
  for (int off = 1; off < 64; off <<= 1) {
    s += __shfl_xor(s, off, 64);
    s2 += __shfl_xor(s2, off, 64);
  }
  if (lane == 0) {
    ws[WS_ROWS + row * 2] = s;
    ws[WS_ROWS + row * 2 + 1] = s2;
  }
}

// ---------------- Kernel H (+fused kG): write gp (out ch 32..63) ----------------
__global__ __launch_bounds__(256) void kH(const float* __restrict__ alpha,
                                          const float* __restrict__ beta,
                                          const float* __restrict__ ws,
                                          float* __restrict__ out) {
  int tid = threadIdx.x;
  int i = blockIdx.x * 256 + tid;          // i < B_*32*N_ by grid construction
  int b = i >> 17;                          // uniform within a block
  // --- fused kG (verbatim reduction order for this batch) ---
  float s = 0.f, s2 = 0.f;
  for (int q = tid; q < N_; q += 256) {
    s += ws[WS_ROWS + (b * N_ + q) * 2];
    s2 += ws[WS_ROWS + (b * N_ + q) * 2 + 1];
  }
  __shared__ float sd[256], sd2[256];
  __shared__ float den_s;
  sd[tid] = s; sd2[tid] = s2;
  __syncthreads();
  for (int st = 128; st > 0; st >>= 1) {
    if (tid < st) { sd[tid] += sd[tid + st]; sd2[tid] += sd2[tid + st]; }
    __syncthreads();
  }
  if (tid == 0) {
    const float M = 2097152.0f;  // N*K*O per batch
    float var = fmaxf((sd2[0] - sd[0] * (sd[0] / M)) / (M - 1.0f), 0.f);
    den_s = sqrtf(var) + 1e-5f;
  }
  __syncthreads();
  float denom = den_s;
  int n = i & (N_ - 1);
  int o = (i >> 12) & 31;
  float al = alpha[o], be = beta[o];
  float v = ws[WS_MAXV + (b * N_ + n) * 32 + o];   // SEL (alpha-selected in kF)
  out[b * 64 * N_ + (32 + o) * N_ + n] = __fadd_rn(__fmul_rn(al, v / denom), be);
}

extern "C" void kernel_launch(void* const* d_in, const int* in_sizes, int n_in,
                              void* d_out, int out_size, void* d_ws, size_t ws_size,
                              hipStream_t stream) {
  const float* xyz   = (const float*)d_in[0];
  const float* w_nn  = (const float*)d_in[1];
  const float* alpha = (const float*)d_in[2];
  const float* beta_a= (const float*)d_in[3];
  const float* w0    = (const float*)d_in[4];
  const float* g0    = (const float*)d_in[5];
  const float* b0    = (const float*)d_in[6];
  const float* w1    = (const float*)d_in[7];
  const float* g1    = (const float*)d_in[8];
  const float* b1    = (const float*)d_in[9];
  float* out = (float*)d_out;
  float* ws  = (float*)d_ws;   // needs WS_TOTAL*4 ~ 8.80 MB (round-0 proven)

  kA<<<64, 256, 0, stream>>>(xyz, ws);
  kC<<<CB_, 256, 0, stream>>>(xyz, w0, g0, b0, w1, ws);
  kE<<<CB_, 256, 0, stream>>>(g1, b1, ws, out);
  kF<<<BN_ / RPB, RPB * 64, 0, stream>>>(xyz, w_nn, alpha, out, ws);
  kH<<<(B_ * 32 * N_ + 255) / 256, 256, 0, stream>>>(alpha, beta_a, ws, out);
}